// Round 1
// baseline (416.805 us; speedup 1.0000x reference)
//
#include <hip/hip_runtime.h>
#include <cstdint>
#include <cmath>

#define NT 1024
#define NB1 16384
#define L1SH 18
#define CAP 8192

// order-preserving float<->uint bijection (ascending float order == ascending uint order)
__device__ __forceinline__ uint32_t f2u(float f) {
    uint32_t b = __float_as_uint(f);
    return (b & 0x80000000u) ? ~b : (b | 0x80000000u);
}
__device__ __forceinline__ float u2f(uint32_t u) {
    uint32_t b = (u & 0x80000000u) ? (u ^ 0x80000000u) : ~u;
    return __uint_as_float(b);
}

__device__ __forceinline__ uint32_t wave_incl_u(uint32_t v) {
    int lane = threadIdx.x & 63;
#pragma unroll
    for (int o = 1; o < 64; o <<= 1) {
        uint32_t t = __shfl_up(v, (unsigned)o);
        if (lane >= o) v += t;
    }
    return v;
}
__device__ __forceinline__ float wave_incl_f(float v) {
    int lane = threadIdx.x & 63;
#pragma unroll
    for (int o = 1; o < 64; o <<= 1) {
        float t = __shfl_up(v, (unsigned)o);
        if (lane >= o) v += t;
    }
    return v;
}

// Descending count-crossing: first bin b (scanning hi -> lo) where
// (count above b) < target && (count above b + h[b]) >= target.
__device__ void wave_desc_count(const uint32_t* h, int hi, int lo, uint32_t target,
                                int* out_bin, uint32_t* out_above) {
    if (threadIdx.x < 64) {
        int lane = threadIdx.x;
        uint32_t S = 0;
        for (int r0 = hi; r0 >= lo; r0 -= 64) {
            int b = r0 - lane;
            uint32_t w = (b >= lo) ? h[b] : 0u;
            uint32_t incl = wave_incl_u(w);
            uint32_t Sb = S + incl - w;  // count strictly above bin b
            bool cross = (Sb < target) && (Sb + w >= target);
            unsigned long long m = __ballot(cross);
            if (m) {
                int l = (int)__ffsll(m) - 1;
                if (lane == l) { *out_bin = b; *out_above = Sb; }
                return;
            }
            S += __shfl(incl, 63);
        }
    }
}

// Descending weighted crossing (same rule, float weights, running base).
__device__ void wave_desc_wcross(const float* h, int hi, int lo, float base, float target,
                                 int* out_bin, float* out_S) {
    if (threadIdx.x < 64) {
        int lane = threadIdx.x;
        float S = base;
        for (int r0 = hi; r0 >= lo; r0 -= 64) {
            int b = r0 - lane;
            float w = (b >= lo) ? h[b] : 0.f;
            float incl = wave_incl_f(w);
            float Sb = S + (incl - w);
            bool cross = (Sb < target) && (Sb + w >= target);
            unsigned long long m = __ballot(cross);
            if (m) {
                int l = (int)__ffsll(m) - 1;
                if (lane == l) { *out_bin = b; *out_S = Sb; }
                return;
            }
            S += __shfl(incl, 63);
        }
        if (lane == 0) *out_S = S;  // exhausted: S = total; out_bin stays -1
    }
}

// Descending VALUE rule: first nonempty bin (exact value) with suffix-above >= target.
__device__ void wave_desc_wvalue(const float* h, int hi, int lo, float base, float target,
                                 int* out_bin, float* out_S) {
    if (threadIdx.x < 64) {
        int lane = threadIdx.x;
        float S = base;
        for (int r0 = hi; r0 >= lo; r0 -= 64) {
            int b = r0 - lane;
            float w = (b >= lo) ? h[b] : 0.f;
            float incl = wave_incl_f(w);
            float Sb = S + (incl - w);  // weight strictly above value b
            bool cross = (w > 0.f) && (Sb >= target);
            unsigned long long m = __ballot(cross);
            if (m) {
                int l = (int)__ffsll(m) - 1;
                if (lane == l) { *out_bin = b; *out_S = Sb; }
                return;
            }
            S += __shfl(incl, 63);
        }
        if (lane == 0) *out_S = S;
    }
}

__device__ float blk_max_f(float v, float* buf) {
    int tid = threadIdx.x;
    buf[tid] = v; __syncthreads();
    for (int o = NT / 2; o > 0; o >>= 1) {
        if (tid < o) buf[tid] = fmaxf(buf[tid], buf[tid + o]);
        __syncthreads();
    }
    float r = buf[0]; __syncthreads();
    return r;
}
__device__ float blk_sum_f(float v, float* buf) {
    int tid = threadIdx.x;
    buf[tid] = v; __syncthreads();
    for (int o = NT / 2; o > 0; o >>= 1) {
        if (tid < o) buf[tid] += buf[tid + o];
        __syncthreads();
    }
    float r = buf[0]; __syncthreads();
    return r;
}

__global__ __launch_bounds__(NT, 1) void Sampler_41669772705843_kernel(
    const float* __restrict__ logits, const float* __restrict__ temps,
    const int* __restrict__ topks, const float* __restrict__ topps,
    const float* __restrict__ minps, const float* __restrict__ noise,
    int* __restrict__ out, int V)
{
    __shared__ uint32_t s_hist[NB1];   // counts in pass A, float weights afterwards (aliased)
    __shared__ uint32_t s_cand[CAP];   // candidate u values; argmax idx buffer at the end
    __shared__ float    s_red[NT];
    __shared__ uint32_t s_h2[512];     // sub-level histograms (counts / float weights)
    __shared__ int      sh_bin;
    __shared__ uint32_t sh_above;
    __shared__ int      sh_nc;
    __shared__ int      sh_binw;
    __shared__ float    sh_S;

    const int row = blockIdx.x;
    const int tid = threadIdx.x;
    const int lane = tid & 63;
    const float t  = temps[row];
    const float pp = topps[row];
    const float mp = minps[row];
    int k = topks[row];
    if (k < 1) k = 1;
    if (k > V) k = V;
    const float* lg = logits + (size_t)row * (size_t)V;
    const float* nz = noise  + (size_t)row * (size_t)V;

    for (int i = tid; i < NB1; i += NT) s_hist[i] = 0u;
    __syncthreads();

    // ---------- Pass A: row max + L1 count histogram ----------
    float lmax = -INFINITY;
    for (int i = tid; i < V; i += NT) {
        float x = lg[i] / t;
        lmax = fmaxf(lmax, x);
        atomicAdd(&s_hist[f2u(x) >> L1SH], 1u);
    }
    const float M = blk_max_f(lmax, s_red);
    const uint32_t umax = f2u(M);
    const int bmax = (int)(umax >> L1SH);

    // ---------- top-k: L1 descent (exact integer counts) ----------
    if (tid == 0) sh_bin = -1;
    __syncthreads();
    wave_desc_count(s_hist, bmax, 0, (uint32_t)k, &sh_bin, &sh_above);
    __syncthreads();
    const int b1 = sh_bin;
    const uint32_t cntHi = sh_above;

    // ---------- Pass B: weighted L1 histogram (all elems) + collect bin-b1 candidates ----------
    float* wh = reinterpret_cast<float*>(s_hist);
    for (int i = tid; i < NB1; i += NT) wh[i] = 0.f;
    if (tid == 0) sh_nc = 0;
    __syncthreads();
    for (int i = tid; i < V; i += NT) {
        float x = lg[i] / t;
        uint32_t u = f2u(x);
        atomicAdd(&wh[u >> L1SH], expf(x - M));
        bool want = ((int)(u >> L1SH) == b1);
        unsigned long long mb = __ballot(want);
        if (want) {
            int leader = (int)__ffsll(mb) - 1;
            int off = (int)__popcll(mb & ((1ull << lane) - 1ull));
            int base = 0;
            if (lane == leader) base = atomicAdd(&sh_nc, (int)__popcll(mb));
            base = __shfl(base, leader);
            int p = base + off;
            if (p < CAP) s_cand[p] = u;
        }
    }
    __syncthreads();
    int nc = sh_nc; if (nc > CAP) nc = CAP;
    const uint32_t kk2 = (uint32_t)k - cntHi;

    // ---------- top-k L2 (bits 17:9) over candidates ----------
    for (int i = tid; i < 512; i += NT) s_h2[i] = 0u;
    __syncthreads();
    for (int i = tid; i < nc; i += NT) atomicAdd(&s_h2[(s_cand[i] >> 9) & 511u], 1u);
    __syncthreads();
    if (tid == 0) sh_bin = -1;
    __syncthreads();
    wave_desc_count(s_h2, 511, 0, kk2, &sh_bin, &sh_above);
    __syncthreads();
    const int c2 = sh_bin;
    const uint32_t kk3 = kk2 - sh_above;

    // ---------- top-k L3 (bits 8:0): exact threshold value ----------
    for (int i = tid; i < 512; i += NT) s_h2[i] = 0u;
    __syncthreads();
    for (int i = tid; i < nc; i += NT) {
        uint32_t u = s_cand[i];
        if ((int)((u >> 9) & 511u) == c2) atomicAdd(&s_h2[u & 511u], 1u);
    }
    __syncthreads();
    if (tid == 0) sh_bin = -1;
    __syncthreads();
    wave_desc_count(s_h2, 511, 0, kk3, &sh_bin, &sh_above);
    __syncthreads();
    const uint32_t uk = ((uint32_t)b1 << L1SH) | ((uint32_t)c2 << 9) | (uint32_t)sh_bin;

    // ---------- kept weight of bin b1, total kept weight W ----------
    float wl = 0.f;
    for (int i = tid; i < nc; i += NT) {
        uint32_t u = s_cand[i];
        if (u >= uk) wl += expf(u2f(u) - M);
    }
    const float Wb1 = blk_sum_f(wl, s_red);
    if (tid == 0) wh[b1] = Wb1;
    __syncthreads();
    float sl = 0.f;
    for (int i = tid; i < NB1; i += NT)
        if (i >= b1 && i <= bmax) sl += wh[i];
    const float W = blk_sum_f(sl, s_red);
    const float pW = pp * W;

    // ---------- top-p: mask kept x iff suffix_strict(x) >= pW ----------
    uint32_t up = 0u;   // mask kept u <= up
    float Z2 = W;
    if (pW <= 0.f) {
        // p == 0: reference masks everything except the forced-kept max
        up = umax - 1u;
        Z2 = 1.0f;
    } else {
        if (tid == 0) sh_binw = -1;
        __syncthreads();
        wave_desc_wcross(wh, bmax, b1, 0.f, pW, &sh_binw, &sh_S);
        __syncthreads();
        const int cs = sh_binw;
        if (cs >= 0) {
            const float S1 = sh_S;
            if (cs != b1) {
                if (tid == 0) sh_nc = 0;
                __syncthreads();
                for (int i = tid; i < V; i += NT) {
                    float x = lg[i] / t;
                    uint32_t u = f2u(x);
                    bool want = (u >= uk) && ((int)(u >> L1SH) == cs);
                    unsigned long long mb = __ballot(want);
                    if (want) {
                        int leader = (int)__ffsll(mb) - 1;
                        int off = (int)__popcll(mb & ((1ull << lane) - 1ull));
                        int base = 0;
                        if (lane == leader) base = atomicAdd(&sh_nc, (int)__popcll(mb));
                        base = __shfl(base, leader);
                        int p = base + off;
                        if (p < CAP) s_cand[p] = u;
                    }
                }
                __syncthreads();
                nc = sh_nc; if (nc > CAP) nc = CAP;
            }
            float* wh2 = reinterpret_cast<float*>(s_h2);
            // L2 weighted (bits 17:9), kept candidates only
            for (int i = tid; i < 512; i += NT) wh2[i] = 0.f;
            __syncthreads();
            for (int i = tid; i < nc; i += NT) {
                uint32_t u = s_cand[i];
                if (u >= uk) atomicAdd(&wh2[(u >> 9) & 511u], expf(u2f(u) - M));
            }
            __syncthreads();
            if (tid == 0) sh_binw = -1;
            __syncthreads();
            wave_desc_wcross(wh2, 511, 0, S1, pW, &sh_binw, &sh_S);
            __syncthreads();
            const int c2p = sh_binw;
            if (c2p < 0) {
                uint32_t basev = (uint32_t)cs << L1SH;
                up = basev ? basev - 1u : 0u;
                Z2 = sh_S;
            } else {
                const float S2 = sh_S;
                // L3 weighted (bits 8:0): exact boundary value, VALUE rule
                for (int i = tid; i < 512; i += NT) wh2[i] = 0.f;
                __syncthreads();
                for (int i = tid; i < nc; i += NT) {
                    uint32_t u = s_cand[i];
                    if (u >= uk && (int)((u >> 9) & 511u) == c2p)
                        atomicAdd(&wh2[u & 511u], expf(u2f(u) - M));
                }
                __syncthreads();
                if (tid == 0) sh_binw = -1;
                __syncthreads();
                wave_desc_wvalue(wh2, 511, 0, S2, pW, &sh_binw, &sh_S);
                __syncthreads();
                if (sh_binw < 0) {
                    uint32_t basev = ((uint32_t)cs << L1SH) | ((uint32_t)c2p << 9);
                    up = basev ? basev - 1u : 0u;
                    Z2 = sh_S;
                } else {
                    up = ((uint32_t)cs << L1SH) | ((uint32_t)c2p << 9) | (uint32_t)sh_binw;
                    Z2 = sh_S;
                }
            }
        }
        if (up >= umax) { up = umax - 1u; Z2 = 1.0f; }  // never mask the max
    }
    __syncthreads();

    // ---------- min_p ----------
    const bool use_mp = (mp > 0.f);
    const float thr = mp * (1.0f / Z2);

    // ---------- Pass D: Z3 = sum of exp(x-M) over finally-kept ----------
    float zl = 0.f;
    for (int i = tid; i < V; i += NT) {
        float x = lg[i] / t;
        uint32_t u = f2u(x);
        if (u >= uk && u > up) {
            float w = expf(x - M);
            if (use_mp && (w / Z2) < thr) continue;
            zl += w;
        }
    }
    const float Z3 = blk_sum_f(zl, s_red);

    // ---------- Pass E: argmax of (exp(x-M)/Z3) / max(noise,1e-10) ----------
    float bs = -1.f; int bi = 0x7fffffff;
    for (int i = tid; i < V; i += NT) {
        float x = lg[i] / t;
        uint32_t u = f2u(x);
        if (u >= uk && u > up) {
            float w = expf(x - M);
            if (use_mp && (w / Z2) < thr) continue;
            float sc = (w / Z3) / fmaxf(nz[i], 1e-10f);
            if (sc > bs) { bs = sc; bi = i; }   // strict > keeps smallest index on ties
        }
    }
    s_red[tid] = bs;
    int* ibuf = reinterpret_cast<int*>(s_cand);
    ibuf[tid] = bi;
    __syncthreads();
    for (int o = NT / 2; o > 0; o >>= 1) {
        if (tid < o) {
            float v2 = s_red[tid + o]; int i2 = ibuf[tid + o];
            if (v2 > s_red[tid] || (v2 == s_red[tid] && i2 < ibuf[tid])) {
                s_red[tid] = v2; ibuf[tid] = i2;
            }
        }
        __syncthreads();
    }
    if (tid == 0) out[row] = ibuf[0];
}

extern "C" void kernel_launch(void* const* d_in, const int* in_sizes, int n_in,
                              void* d_out, int out_size, void* d_ws, size_t ws_size,
                              hipStream_t stream) {
    const float* logits = (const float*)d_in[0];
    const float* temps  = (const float*)d_in[1];
    const int*   topks  = (const int*)d_in[2];
    const float* topps  = (const float*)d_in[3];
    const float* minps  = (const float*)d_in[4];
    const float* noise  = (const float*)d_in[5];
    const int B = in_sizes[1];
    const int V = in_sizes[0] / B;
    Sampler_41669772705843_kernel<<<B, NT, 0, stream>>>(
        logits, temps, topks, topps, minps, noise, (int*)d_out, V);
}

// Round 2
// 88.504 us; speedup vs baseline: 4.7094x; 4.7094x over previous
//
#include <hip/hip_runtime.h>
#include <cstdint>
#include <cmath>

// ---------------- common helpers ----------------

#define SLICES 16
#define SUBCAP 1024
#define CAPR (SLICES * SUBCAP)
#define NB 4096
#define L1SH 20

static __device__ __forceinline__ uint32_t f2u(float f) {
    uint32_t b = __float_as_uint(f);
    return (b & 0x80000000u) ? ~b : (b | 0x80000000u);
}
static __device__ __forceinline__ float u2f(uint32_t u) {
    uint32_t b = (u & 0x80000000u) ? (u ^ 0x80000000u) : ~u;
    return __uint_as_float(b);
}

static __device__ __forceinline__ uint32_t wave_incl_u(uint32_t v) {
    int lane = threadIdx.x & 63;
#pragma unroll
    for (int o = 1; o < 64; o <<= 1) {
        uint32_t t = __shfl_up(v, (unsigned)o);
        if (lane >= o) v += t;
    }
    return v;
}
static __device__ __forceinline__ float wave_incl_f(float v) {
    int lane = threadIdx.x & 63;
#pragma unroll
    for (int o = 1; o < 64; o <<= 1) {
        float t = __shfl_up(v, (unsigned)o);
        if (lane >= o) v += t;
    }
    return v;
}

// Descending count-crossing: first bin b (hi -> lo) with above < target <= above + h[b].
static __device__ void wave_desc_count(const uint32_t* h, int hi, int lo, uint32_t target,
                                       int* out_bin, uint32_t* out_above) {
    if (threadIdx.x < 64) {
        int lane = threadIdx.x;
        uint32_t S = 0;
        for (int r0 = hi; r0 >= lo; r0 -= 64) {
            int b = r0 - lane;
            uint32_t w = (b >= lo) ? h[b] : 0u;
            uint32_t incl = wave_incl_u(w);
            uint32_t Sb = S + incl - w;
            bool cross = (Sb < target) && (Sb + w >= target);
            unsigned long long m = __ballot(cross);
            if (m) {
                int l = (int)__ffsll(m) - 1;
                if (lane == l) { *out_bin = b; *out_above = Sb; }
                return;
            }
            S += __shfl(incl, 63);
        }
    }
}

// Descending weighted crossing (float weights, running base).
static __device__ void wave_desc_wcross(const float* h, int hi, int lo, float base, float target,
                                        int* out_bin, float* out_S) {
    if (threadIdx.x < 64) {
        int lane = threadIdx.x;
        float S = base;
        for (int r0 = hi; r0 >= lo; r0 -= 64) {
            int b = r0 - lane;
            float w = (b >= lo) ? h[b] : 0.f;
            float incl = wave_incl_f(w);
            float Sb = S + (incl - w);
            bool cross = (Sb < target) && (Sb + w >= target);
            unsigned long long m = __ballot(cross);
            if (m) {
                int l = (int)__ffsll(m) - 1;
                if (lane == l) { *out_bin = b; *out_S = Sb; }
                return;
            }
            S += __shfl(incl, 63);
        }
        if (lane == 0) *out_S = S;
    }
}

// Descending VALUE rule: first nonempty bin with suffix-strictly-above >= target.
static __device__ void wave_desc_wvalue(const float* h, int hi, int lo, float base, float target,
                                        int* out_bin, float* out_S) {
    if (threadIdx.x < 64) {
        int lane = threadIdx.x;
        float S = base;
        for (int r0 = hi; r0 >= lo; r0 -= 64) {
            int b = r0 - lane;
            float w = (b >= lo) ? h[b] : 0.f;
            float incl = wave_incl_f(w);
            float Sb = S + (incl - w);
            bool cross = (w > 0.f) && (Sb >= target);
            unsigned long long m = __ballot(cross);
            if (m) {
                int l = (int)__ffsll(m) - 1;
                if (lane == l) { *out_bin = b; *out_S = Sb; }
                return;
            }
            S += __shfl(incl, 63);
        }
        if (lane == 0) *out_S = S;
    }
}

// ---------------- pipeline kernels ----------------

// K1: per-slice scan -> global count histogram + row max (order-preserving uint).
__global__ __launch_bounds__(256) void k1_hist(
    const float* __restrict__ logits, const float* __restrict__ temps,
    uint32_t* __restrict__ hist, uint32_t* __restrict__ rowmaxu,
    int V, int sliceLen)
{
    const int row = blockIdx.y, slice = blockIdx.x, tid = threadIdx.x;
    __shared__ uint32_t h[NB];
    __shared__ uint32_t rmx[256];
    for (int i = tid; i < NB; i += 256) h[i] = 0u;
    __syncthreads();
    const float t = temps[row];
    const float* lg = logits + (size_t)row * (size_t)V;
    int base = slice * sliceLen;
    int len = V - base; if (len < 0) len = 0; if (len > sliceLen) len = sliceLen;
    uint32_t um = 0u;
    if (len > 0) {
        if ((((uintptr_t)(lg + base)) & 15u) == 0) {
            int n4 = len >> 2;
            const float4* p4 = (const float4*)(lg + base);
            for (int i = tid; i < n4; i += 256) {
                float4 v = p4[i];
                uint32_t u0 = f2u(v.x / t), u1 = f2u(v.y / t);
                uint32_t u2 = f2u(v.z / t), u3 = f2u(v.w / t);
                atomicAdd(&h[u0 >> L1SH], 1u); atomicAdd(&h[u1 >> L1SH], 1u);
                atomicAdd(&h[u2 >> L1SH], 1u); atomicAdd(&h[u3 >> L1SH], 1u);
                uint32_t m01 = u0 > u1 ? u0 : u1, m23 = u2 > u3 ? u2 : u3;
                uint32_t m = m01 > m23 ? m01 : m23;
                if (m > um) um = m;
            }
            for (int i = base + (n4 << 2) + tid; i < base + len; i += 256) {
                uint32_t u = f2u(lg[i] / t);
                atomicAdd(&h[u >> L1SH], 1u);
                if (u > um) um = u;
            }
        } else {
            for (int i = base + tid; i < base + len; i += 256) {
                uint32_t u = f2u(lg[i] / t);
                atomicAdd(&h[u >> L1SH], 1u);
                if (u > um) um = u;
            }
        }
    }
    rmx[tid] = um; __syncthreads();
    for (int o = 128; o > 0; o >>= 1) {
        if (tid < o) { if (rmx[tid + o] > rmx[tid]) rmx[tid] = rmx[tid + o]; }
        __syncthreads();
    }
    if (tid == 0) atomicMax(&rowmaxu[row], rmx[0]);
    for (int i = tid; i < NB; i += 256) {
        uint32_t c = h[i];
        if (c) atomicAdd(&hist[(size_t)row * NB + i], c);
    }
}

// K2: per-row coarse descent -> bin base containing the k-th largest.
__global__ void k2_findbin(const uint32_t* __restrict__ hist, const int* __restrict__ topks,
                           const uint32_t* __restrict__ rowmaxu, uint32_t* __restrict__ ubase, int V)
{
    const int row = blockIdx.x;
    const int lane = threadIdx.x;  // block = 64
    int k = topks[row]; if (k < 1) k = 1; if (k > V) k = V;
    const uint32_t* h = hist + (size_t)row * NB;
    int hi = (int)(rowmaxu[row] >> L1SH);
    uint32_t S = 0;
    for (int r0 = hi; r0 >= 0; r0 -= 64) {
        int b = r0 - lane;
        uint32_t w = (b >= 0) ? h[b] : 0u;
        uint32_t incl = wave_incl_u(w);
        uint32_t Sb = S + incl - w;
        bool cross = (Sb < (uint32_t)k) && (Sb + w >= (uint32_t)k);
        unsigned long long m = __ballot(cross);
        if (m) {
            int l = (int)__ffsll(m) - 1;
            if (lane == l) ubase[row] = (uint32_t)b << L1SH;
            return;
        }
        S += __shfl(incl, 63);
    }
    if (lane == 0) ubase[row] = 0u;
}

// K3: re-scan, deterministically compact (u, idx) with u >= ubase into per-slice buffers.
__global__ __launch_bounds__(256) void k3_collect(
    const float* __restrict__ logits, const float* __restrict__ temps,
    const uint32_t* __restrict__ ubase, uint32_t* __restrict__ cand_u,
    int* __restrict__ cand_ix, uint32_t* __restrict__ candCnt, int V, int sliceLen)
{
    const int row = blockIdx.y, slice = blockIdx.x, tid = threadIdx.x;
    const int lane = tid & 63, wv = tid >> 6;
    const float t = temps[row];
    const uint32_t ub = ubase[row];
    const float* lg = logits + (size_t)row * (size_t)V;
    uint32_t* cu = cand_u + ((size_t)row * SLICES + slice) * SUBCAP;
    int* cix = cand_ix + ((size_t)row * SLICES + slice) * SUBCAP;
    __shared__ int wsum[4];
    __shared__ int s_base;
    if (tid == 0) s_base = 0;
    __syncthreads();
    int base = slice * sliceLen;
    int len = V - base; if (len < 0) len = 0; if (len > sliceLen) len = sliceLen;
    const bool al = ((((uintptr_t)(lg + base)) & 15u) == 0);
    for (int c0 = 0; c0 < len; c0 += 1024) {
        int i0 = base + c0 + tid * 4;
        uint32_t uu[4]; int gi[4]; int cnt = 0;
        if (al && (c0 + tid * 4 + 4 <= len)) {
            float4 v = *(const float4*)(lg + i0);
            float xs[4] = {v.x, v.y, v.z, v.w};
#pragma unroll
            for (int j = 0; j < 4; j++) {
                uint32_t u = f2u(xs[j] / t);
                if (u >= ub) { uu[cnt] = u; gi[cnt] = i0 + j; cnt++; }
            }
        } else {
#pragma unroll
            for (int j = 0; j < 4; j++) {
                int i = i0 + j;
                if (i < base + len) {
                    uint32_t u = f2u(lg[i] / t);
                    if (u >= ub) { uu[cnt] = u; gi[cnt] = i; cnt++; }
                }
            }
        }
        // deterministic block-wide compaction: wave shfl scan + wave totals
        int inc = cnt;
#pragma unroll
        for (int o = 1; o < 64; o <<= 1) {
            int tv = __shfl_up(inc, (unsigned)o);
            if (lane >= o) inc += tv;
        }
        if (lane == 63) wsum[wv] = inc;
        __syncthreads();
        int woff = 0;
        for (int w = 0; w < wv; w++) woff += wsum[w];
        int tot = wsum[0] + wsum[1] + wsum[2] + wsum[3];
        int p0 = s_base + woff + inc - cnt;
        for (int j = 0; j < cnt; j++) {
            int p = p0 + j;
            if (p < SUBCAP) { cu[p] = uu[j]; cix[p] = gi[j]; }
        }
        __syncthreads();
        if (tid == 0) s_base += tot;
        __syncthreads();
    }
    if (tid == 0) {
        int c = s_base; if (c > SUBCAP) c = SUBCAP;
        candCnt[row * SLICES + slice] = (uint32_t)c;
    }
}

// K4: per-row finalize from compact candidates: exact top-k, top-p, min-p, noise-argmax.
__global__ __launch_bounds__(1024, 1) void k4_final(
    const int* __restrict__ topks, const float* __restrict__ topps,
    const float* __restrict__ minps, const float* __restrict__ noise,
    const uint32_t* __restrict__ rowmaxu, const uint32_t* __restrict__ candCnt,
    const uint32_t* __restrict__ cand_u, const int* __restrict__ cand_ix,
    int* __restrict__ out, int V)
{
    const int row = blockIdx.x, tid = threadIdx.x;
    __shared__ uint32_t s_u[CAPR];
    __shared__ int s_off[SLICES + 1];
    __shared__ uint32_t h[256];
    __shared__ float fh[256];
    __shared__ float red[1024];
    __shared__ unsigned long long redu[1024];
    __shared__ int sh_bin; __shared__ uint32_t sh_above; __shared__ float sh_S;

    if (tid == 0) {
        int a = 0;
        for (int s = 0; s < SLICES; s++) { s_off[s] = a; a += (int)candCnt[row * SLICES + s]; }
        s_off[SLICES] = a;
    }
    __syncthreads();
    const int n = s_off[SLICES];
    for (int s = 0; s < SLICES; s++) {
        const int o0 = s_off[s], c = s_off[s + 1] - o0;
        const uint32_t* src = cand_u + ((size_t)row * SLICES + s) * SUBCAP;
        for (int j = tid; j < c; j += 1024) s_u[o0 + j] = src[j];
    }
    __syncthreads();

    int k = topks[row]; if (k < 1) k = 1; if (k > V) k = V;
    const uint32_t umax = rowmaxu[row];

    // ---- exact top-k threshold uk: 4-level radix descent on counts ----
    uint32_t prefix = 0u; uint32_t tk = (uint32_t)k;
    for (int l = 0; l < 4; l++) {
        const int sh = 24 - 8 * l;
        for (int i = tid; i < 256; i += 1024) h[i] = 0u;
        __syncthreads();
        for (int i = tid; i < n; i += 1024) {
            uint32_t u = s_u[i];
            if (l == 0 || (u >> (sh + 8)) == prefix) atomicAdd(&h[(u >> sh) & 255u], 1u);
        }
        __syncthreads();
        if (tid == 0) { sh_bin = -1; sh_above = 0u; }
        __syncthreads();
        wave_desc_count(h, 255, 0, tk, &sh_bin, &sh_above);
        __syncthreads();
        int b = sh_bin; if (b < 0) b = 0;
        uint32_t ab = sh_above;
        prefix = (prefix << 8) | (uint32_t)b;
        tk = (tk > ab) ? (tk - ab) : 1u;
        __syncthreads();
    }
    const uint32_t uk = prefix;

    // ---- W over top-k kept ----
    float wl = 0.f;
    for (int i = tid; i < n; i += 1024) { uint32_t u = s_u[i]; if (u >= uk) wl += expf(u2f(u)); }
    red[tid] = wl; __syncthreads();
    for (int o = 512; o > 0; o >>= 1) { if (tid < o) red[tid] += red[tid + o]; __syncthreads(); }
    const float W = red[0]; __syncthreads();
    const float pW = topps[row] * W;

    // ---- top-p boundary value up (mask kept u <= up) ----
    uint32_t up = 0u;
    if (pW <= 0.f) {
        up = umax - 1u;
    } else {
        uint32_t pfx = 0u; float Sbase = 0.f; bool done = false;
        for (int l = 0; l < 4 && !done; l++) {
            const int sh = 24 - 8 * l;
            for (int i = tid; i < 256; i += 1024) fh[i] = 0.f;
            __syncthreads();
            for (int i = tid; i < n; i += 1024) {
                uint32_t u = s_u[i];
                if (u >= uk && (l == 0 || (u >> (sh + 8)) == pfx))
                    atomicAdd(&fh[(u >> sh) & 255u], expf(u2f(u)));
            }
            __syncthreads();
            if (tid == 0) { sh_bin = -1; sh_S = 0.f; }
            __syncthreads();
            if (l < 3) wave_desc_wcross(fh, 255, 0, Sbase, pW, &sh_bin, &sh_S);
            else       wave_desc_wvalue(fh, 255, 0, Sbase, pW, &sh_bin, &sh_S);
            __syncthreads();
            int b = sh_bin;
            if (b < 0) {
                if (l == 0) up = 0u;                       // suffix never reaches pW: mask nothing
                else up = (pfx << (sh + 8)) - 1u;          // mask everything below current bin
                done = true;
            } else {
                if (l == 3) up = (pfx << 8) | (uint32_t)b; // exact boundary value
                pfx = (pfx << 8) | (uint32_t)b;
                Sbase = sh_S;
            }
            __syncthreads();
        }
        if (up >= umax) up = umax - 1u;                    // never mask the max
    }

    // ---- min-p ----
    const float mp = minps[row];
    float z2l = 0.f;
    for (int i = tid; i < n; i += 1024) {
        uint32_t u = s_u[i];
        if (u >= uk && u > up) z2l += expf(u2f(u));
    }
    red[tid] = z2l; __syncthreads();
    for (int o = 512; o > 0; o >>= 1) { if (tid < o) red[tid] += red[tid + o]; __syncthreads(); }
    const float Z2 = red[0]; __syncthreads();
    const float maxw = expf(u2f(umax));
    const float A = (mp > 0.f) ? (maxw / Z2) * mp : 0.f;

    // ---- Z3 over finally-kept ----
    float z3l = 0.f;
    for (int i = tid; i < n; i += 1024) {
        uint32_t u = s_u[i];
        if (u >= uk && u > up) {
            float w = expf(u2f(u));
            if (!(mp > 0.f && (w / Z2) < A)) z3l += w;
        }
    }
    red[tid] = z3l; __syncthreads();
    for (int o = 512; o > 0; o >>= 1) { if (tid < o) red[tid] += red[tid + o]; __syncthreads(); }
    const float Z3 = red[0]; __syncthreads();

    // ---- final argmax of (w/Z3)/max(noise,1e-10); smallest index on ties ----
    unsigned long long best = 0ull;
    for (int p = tid; p < n; p += 1024) {
        uint32_t u = s_u[p];
        if (u >= uk && u > up) {
            float w = expf(u2f(u));
            if (!(mp > 0.f && (w / Z2) < A)) {
                int s = 0;
                while (s < SLICES - 1 && s_off[s + 1] <= p) s++;
                int idx = cand_ix[((size_t)row * SLICES + s) * SUBCAP + (p - s_off[s])];
                float nz = fmaxf(noise[(size_t)row * V + idx], 1e-10f);
                float sc = (w / Z3) / nz;
                unsigned long long pk =
                    ((unsigned long long)__float_as_uint(sc) << 32) |
                    (unsigned long long)(~(uint32_t)idx);
                if (pk > best) best = pk;
            }
        }
    }
    redu[tid] = best; __syncthreads();
    for (int o = 512; o > 0; o >>= 1) {
        if (tid < o) { if (redu[tid + o] > redu[tid]) redu[tid] = redu[tid + o]; }
        __syncthreads();
    }
    if (tid == 0) out[row] = (int)(~(uint32_t)(redu[0] & 0xffffffffull));
}

// ---------------- fallback: round-1 single-kernel path (used if ws too small) ----------------

#define FNT 1024
#define FNB1 16384
#define FL1SH 18
#define FCAP 8192

static __device__ float fblk_max_f(float v, float* buf) {
    int tid = threadIdx.x;
    buf[tid] = v; __syncthreads();
    for (int o = FNT / 2; o > 0; o >>= 1) {
        if (tid < o) buf[tid] = fmaxf(buf[tid], buf[tid + o]);
        __syncthreads();
    }
    float r = buf[0]; __syncthreads();
    return r;
}
static __device__ float fblk_sum_f(float v, float* buf) {
    int tid = threadIdx.x;
    buf[tid] = v; __syncthreads();
    for (int o = FNT / 2; o > 0; o >>= 1) {
        if (tid < o) buf[tid] += buf[tid + o];
        __syncthreads();
    }
    float r = buf[0]; __syncthreads();
    return r;
}

__global__ __launch_bounds__(FNT, 1) void sampler_fallback_kernel(
    const float* __restrict__ logits, const float* __restrict__ temps,
    const int* __restrict__ topks, const float* __restrict__ topps,
    const float* __restrict__ minps, const float* __restrict__ noise,
    int* __restrict__ out, int V)
{
    __shared__ uint32_t s_hist[FNB1];
    __shared__ uint32_t s_cand[FCAP];
    __shared__ float    s_red[FNT];
    __shared__ uint32_t s_h2[512];
    __shared__ int      sh_bin;
    __shared__ uint32_t sh_above;
    __shared__ int      sh_nc;
    __shared__ int      sh_binw;
    __shared__ float    sh_S;

    const int row = blockIdx.x;
    const int tid = threadIdx.x;
    const int lane = tid & 63;
    const float t  = temps[row];
    const float pp = topps[row];
    const float mp = minps[row];
    int k = topks[row];
    if (k < 1) k = 1;
    if (k > V) k = V;
    const float* lg = logits + (size_t)row * (size_t)V;
    const float* nz = noise  + (size_t)row * (size_t)V;

    for (int i = tid; i < FNB1; i += FNT) s_hist[i] = 0u;
    __syncthreads();

    float lmax = -INFINITY;
    for (int i = tid; i < V; i += FNT) {
        float x = lg[i] / t;
        lmax = fmaxf(lmax, x);
        atomicAdd(&s_hist[f2u(x) >> FL1SH], 1u);
    }
    const float M = fblk_max_f(lmax, s_red);
    const uint32_t umax = f2u(M);
    const int bmax = (int)(umax >> FL1SH);

    if (tid == 0) sh_bin = -1;
    __syncthreads();
    wave_desc_count(s_hist, bmax, 0, (uint32_t)k, &sh_bin, &sh_above);
    __syncthreads();
    const int b1 = sh_bin;
    const uint32_t cntHi = sh_above;

    float* wh = reinterpret_cast<float*>(s_hist);
    for (int i = tid; i < FNB1; i += FNT) wh[i] = 0.f;
    if (tid == 0) sh_nc = 0;
    __syncthreads();
    for (int i = tid; i < V; i += FNT) {
        float x = lg[i] / t;
        uint32_t u = f2u(x);
        atomicAdd(&wh[u >> FL1SH], expf(x - M));
        bool want = ((int)(u >> FL1SH) == b1);
        unsigned long long mb = __ballot(want);
        if (want) {
            int leader = (int)__ffsll(mb) - 1;
            int off = (int)__popcll(mb & ((1ull << lane) - 1ull));
            int base = 0;
            if (lane == leader) base = atomicAdd(&sh_nc, (int)__popcll(mb));
            base = __shfl(base, leader);
            int p = base + off;
            if (p < FCAP) s_cand[p] = u;
        }
    }
    __syncthreads();
    int nc = sh_nc; if (nc > FCAP) nc = FCAP;
    const uint32_t kk2 = (uint32_t)k - cntHi;

    for (int i = tid; i < 512; i += FNT) s_h2[i] = 0u;
    __syncthreads();
    for (int i = tid; i < nc; i += FNT) atomicAdd(&s_h2[(s_cand[i] >> 9) & 511u], 1u);
    __syncthreads();
    if (tid == 0) sh_bin = -1;
    __syncthreads();
    wave_desc_count(s_h2, 511, 0, kk2, &sh_bin, &sh_above);
    __syncthreads();
    const int c2 = sh_bin;
    const uint32_t kk3 = kk2 - sh_above;

    for (int i = tid; i < 512; i += FNT) s_h2[i] = 0u;
    __syncthreads();
    for (int i = tid; i < nc; i += FNT) {
        uint32_t u = s_cand[i];
        if ((int)((u >> 9) & 511u) == c2) atomicAdd(&s_h2[u & 511u], 1u);
    }
    __syncthreads();
    if (tid == 0) sh_bin = -1;
    __syncthreads();
    wave_desc_count(s_h2, 511, 0, kk3, &sh_bin, &sh_above);
    __syncthreads();
    const uint32_t uk = ((uint32_t)b1 << FL1SH) | ((uint32_t)c2 << 9) | (uint32_t)sh_bin;

    float wl = 0.f;
    for (int i = tid; i < nc; i += FNT) {
        uint32_t u = s_cand[i];
        if (u >= uk) wl += expf(u2f(u) - M);
    }
    const float Wb1 = fblk_sum_f(wl, s_red);
    if (tid == 0) wh[b1] = Wb1;
    __syncthreads();
    float sl = 0.f;
    for (int i = tid; i < FNB1; i += FNT)
        if (i >= b1 && i <= bmax) sl += wh[i];
    const float W = fblk_sum_f(sl, s_red);
    const float pW = pp * W;

    uint32_t up = 0u;
    float Z2 = W;
    if (pW <= 0.f) {
        up = umax - 1u;
        Z2 = 1.0f;
    } else {
        if (tid == 0) sh_binw = -1;
        __syncthreads();
        wave_desc_wcross(wh, bmax, b1, 0.f, pW, &sh_binw, &sh_S);
        __syncthreads();
        const int cs = sh_binw;
        if (cs >= 0) {
            const float S1 = sh_S;
            if (cs != b1) {
                if (tid == 0) sh_nc = 0;
                __syncthreads();
                for (int i = tid; i < V; i += FNT) {
                    float x = lg[i] / t;
                    uint32_t u = f2u(x);
                    bool want = (u >= uk) && ((int)(u >> FL1SH) == cs);
                    unsigned long long mb = __ballot(want);
                    if (want) {
                        int leader = (int)__ffsll(mb) - 1;
                        int off = (int)__popcll(mb & ((1ull << lane) - 1ull));
                        int base = 0;
                        if (lane == leader) base = atomicAdd(&sh_nc, (int)__popcll(mb));
                        base = __shfl(base, leader);
                        int p = base + off;
                        if (p < FCAP) s_cand[p] = u;
                    }
                }
                __syncthreads();
                nc = sh_nc; if (nc > FCAP) nc = FCAP;
            }
            float* wh2 = reinterpret_cast<float*>(s_h2);
            for (int i = tid; i < 512; i += FNT) wh2[i] = 0.f;
            __syncthreads();
            for (int i = tid; i < nc; i += FNT) {
                uint32_t u = s_cand[i];
                if (u >= uk) atomicAdd(&wh2[(u >> 9) & 511u], expf(u2f(u) - M));
            }
            __syncthreads();
            if (tid == 0) sh_binw = -1;
            __syncthreads();
            wave_desc_wcross(wh2, 511, 0, S1, pW, &sh_binw, &sh_S);
            __syncthreads();
            const int c2p = sh_binw;
            if (c2p < 0) {
                uint32_t basev = (uint32_t)cs << FL1SH;
                up = basev ? basev - 1u : 0u;
                Z2 = sh_S;
            } else {
                const float S2 = sh_S;
                for (int i = tid; i < 512; i += FNT) wh2[i] = 0.f;
                __syncthreads();
                for (int i = tid; i < nc; i += FNT) {
                    uint32_t u = s_cand[i];
                    if (u >= uk && (int)((u >> 9) & 511u) == c2p)
                        atomicAdd(&wh2[u & 511u], expf(u2f(u) - M));
                }
                __syncthreads();
                if (tid == 0) sh_binw = -1;
                __syncthreads();
                wave_desc_wvalue(wh2, 511, 0, S2, pW, &sh_binw, &sh_S);
                __syncthreads();
                if (sh_binw < 0) {
                    uint32_t basev = ((uint32_t)cs << FL1SH) | ((uint32_t)c2p << 9);
                    up = basev ? basev - 1u : 0u;
                    Z2 = sh_S;
                } else {
                    up = ((uint32_t)cs << FL1SH) | ((uint32_t)c2p << 9) | (uint32_t)sh_binw;
                    Z2 = sh_S;
                }
            }
        }
        if (up >= umax) { up = umax - 1u; Z2 = 1.0f; }
    }
    __syncthreads();

    const bool use_mp = (mp > 0.f);
    const float thr = mp * (1.0f / Z2);

    float zl = 0.f;
    for (int i = tid; i < V; i += FNT) {
        float x = lg[i] / t;
        uint32_t u = f2u(x);
        if (u >= uk && u > up) {
            float w = expf(x - M);
            if (use_mp && (w / Z2) < thr) continue;
            zl += w;
        }
    }
    const float Z3 = fblk_sum_f(zl, s_red);

    float bs = -1.f; int bi = 0x7fffffff;
    for (int i = tid; i < V; i += FNT) {
        float x = lg[i] / t;
        uint32_t u = f2u(x);
        if (u >= uk && u > up) {
            float w = expf(x - M);
            if (use_mp && (w / Z2) < thr) continue;
            float sc = (w / Z3) / fmaxf(nz[i], 1e-10f);
            if (sc > bs) { bs = sc; bi = i; }
        }
    }
    s_red[tid] = bs;
    int* ibuf = reinterpret_cast<int*>(s_cand);
    ibuf[tid] = bi;
    __syncthreads();
    for (int o = FNT / 2; o > 0; o >>= 1) {
        if (tid < o) {
            float v2 = s_red[tid + o]; int i2 = ibuf[tid + o];
            if (v2 > s_red[tid] || (v2 == s_red[tid] && i2 < ibuf[tid])) {
                s_red[tid] = v2; ibuf[tid] = i2;
            }
        }
        __syncthreads();
    }
    if (tid == 0) out[row] = ibuf[0];
}

// ---------------- launch ----------------

extern "C" void kernel_launch(void* const* d_in, const int* in_sizes, int n_in,
                              void* d_out, int out_size, void* d_ws, size_t ws_size,
                              hipStream_t stream) {
    const float* logits = (const float*)d_in[0];
    const float* temps  = (const float*)d_in[1];
    const int*   topks  = (const int*)d_in[2];
    const float* topps  = (const float*)d_in[3];
    const float* minps  = (const float*)d_in[4];
    const float* noise  = (const float*)d_in[5];
    const int B = in_sizes[1];
    const int V = in_sizes[0] / B;
    int* out = (int*)d_out;

    const size_t offHist = 0;
    const size_t offMax  = offHist + (size_t)B * NB * 4;
    const size_t offCnt  = offMax  + (size_t)B * 4;
    const size_t offUB   = offCnt  + (size_t)B * SLICES * 4;
    const size_t offCU   = offUB   + (size_t)B * 4;
    const size_t offCI   = offCU   + (size_t)B * CAPR * 4;
    const size_t need    = offCI   + (size_t)B * CAPR * 4;

    if (ws_size >= need) {
        char* ws = (char*)d_ws;
        uint32_t* hist    = (uint32_t*)(ws + offHist);
        uint32_t* rowmaxu = (uint32_t*)(ws + offMax);
        uint32_t* candCnt = (uint32_t*)(ws + offCnt);
        uint32_t* ubase   = (uint32_t*)(ws + offUB);
        uint32_t* cand_u  = (uint32_t*)(ws + offCU);
        int*      cand_ix = (int*)(ws + offCI);

        hipMemsetAsync(ws, 0, offCU, stream);  // hist + rowmax + counts + ubase
        const int sliceLen = (((V + SLICES - 1) / SLICES) + 3) & ~3;
        dim3 gslice(SLICES, B);
        k1_hist<<<gslice, 256, 0, stream>>>(logits, temps, hist, rowmaxu, V, sliceLen);
        k2_findbin<<<B, 64, 0, stream>>>(hist, topks, rowmaxu, ubase, V);
        k3_collect<<<gslice, 256, 0, stream>>>(logits, temps, ubase, cand_u, cand_ix, candCnt, V, sliceLen);
        k4_final<<<B, 1024, 0, stream>>>(topks, topps, minps, noise, rowmaxu, candCnt,
                                         cand_u, cand_ix, out, V);
    } else {
        sampler_fallback_kernel<<<B, FNT, 0, stream>>>(logits, temps, topks, topps, minps, noise, out, V);
    }
}

// Round 3
// 81.617 us; speedup vs baseline: 5.1069x; 1.0844x over previous
//
#include <hip/hip_runtime.h>
#include <cstdint>
#include <cmath>

// ---------------- tunables ----------------
#define SLICES 16
#define SUBCAP 768
#define CAPT (SLICES * SUBCAP)
#define NBL 4096      // local histogram bins (u >> 20)
#define LBSH 20
#define CLOC 256u     // per-slice local top-count to cover global top-k (<=1999)

// order-preserving float<->uint bijection
static __device__ __forceinline__ uint32_t f2u(float f) {
    uint32_t b = __float_as_uint(f);
    return (b & 0x80000000u) ? ~b : (b | 0x80000000u);
}
static __device__ __forceinline__ float u2f(uint32_t u) {
    uint32_t b = (u & 0x80000000u) ? (u ^ 0x80000000u) : ~u;
    return __uint_as_float(b);
}

static __device__ __forceinline__ uint32_t wave_incl_u(uint32_t v) {
    int lane = threadIdx.x & 63;
#pragma unroll
    for (int o = 1; o < 64; o <<= 1) {
        uint32_t t = __shfl_up(v, (unsigned)o);
        if (lane >= o) v += t;
    }
    return v;
}
static __device__ __forceinline__ float wave_incl_f(float v) {
    int lane = threadIdx.x & 63;
#pragma unroll
    for (int o = 1; o < 64; o <<= 1) {
        float t = __shfl_up(v, (unsigned)o);
        if (lane >= o) v += t;
    }
    return v;
}

// Descending count-crossing: first bin b (hi->lo) with above < target <= above + h[b].
// Self-writes out_bin=-1 (and out_above=S) on exhaustion (no caller reset needed).
static __device__ void wave_desc_count(const uint32_t* h, int hi, int lo, uint32_t target,
                                       int* out_bin, uint32_t* out_above) {
    if (threadIdx.x < 64) {
        int lane = threadIdx.x;
        uint32_t S = 0;
        for (int r0 = hi; r0 >= lo; r0 -= 64) {
            int b = r0 - lane;
            uint32_t w = (b >= lo) ? h[b] : 0u;
            uint32_t incl = wave_incl_u(w);
            uint32_t Sb = S + incl - w;
            bool cross = (Sb < target) && (Sb + w >= target);
            unsigned long long m = __ballot(cross);
            if (m) {
                int l = (int)__ffsll(m) - 1;
                if (lane == l) { *out_bin = b; *out_above = Sb; }
                return;
            }
            S += __shfl(incl, 63);
        }
        if (lane == 0) { *out_bin = -1; *out_above = S; }
    }
}

// Descending weighted crossing. Self-writes -1 / total on exhaustion.
static __device__ void wave_desc_wcross(const float* h, int hi, int lo, float base, float target,
                                        int* out_bin, float* out_S) {
    if (threadIdx.x < 64) {
        int lane = threadIdx.x;
        float S = base;
        for (int r0 = hi; r0 >= lo; r0 -= 64) {
            int b = r0 - lane;
            float w = (b >= lo) ? h[b] : 0.f;
            float incl = wave_incl_f(w);
            float Sb = S + (incl - w);
            bool cross = (Sb < target) && (Sb + w >= target);
            unsigned long long m = __ballot(cross);
            if (m) {
                int l = (int)__ffsll(m) - 1;
                if (lane == l) { *out_bin = b; *out_S = Sb; }
                return;
            }
            S += __shfl(incl, 63);
        }
        if (lane == 0) { *out_bin = -1; *out_S = S; }
    }
}

// Descending VALUE rule: first nonempty bin with suffix-strictly-above >= target.
static __device__ void wave_desc_wvalue(const float* h, int hi, int lo, float base, float target,
                                        int* out_bin, float* out_S) {
    if (threadIdx.x < 64) {
        int lane = threadIdx.x;
        float S = base;
        for (int r0 = hi; r0 >= lo; r0 -= 64) {
            int b = r0 - lane;
            float w = (b >= lo) ? h[b] : 0.f;
            float incl = wave_incl_f(w);
            float Sb = S + (incl - w);
            bool cross = (w > 0.f) && (Sb >= target);
            unsigned long long m = __ballot(cross);
            if (m) {
                int l = (int)__ffsll(m) - 1;
                if (lane == l) { *out_bin = b; *out_S = Sb; }
                return;
            }
            S += __shfl(incl, 63);
        }
        if (lane == 0) { *out_bin = -1; *out_S = S; }
    }
}

// ---------------- K1': stream + local top-C collect (single HBM pass) ----------------

__global__ __launch_bounds__(256) void k1_collect(
    const float* __restrict__ logits, const float* __restrict__ temps,
    uint32_t* __restrict__ cand_u, int* __restrict__ cand_ix,
    uint32_t* __restrict__ candCnt, int V, int sliceLen)
{
    const int row = blockIdx.y, slice = blockIdx.x, tid = threadIdx.x;
    const int lane = tid & 63, wv = tid >> 6;
    __shared__ uint32_t h[NBL];
    __shared__ uint32_t rmx[4];
    __shared__ int wsum[4];
    __shared__ int s_base;
    __shared__ int sh_lb;

    const int base = slice * sliceLen;
    int len = V - base;
    if (len > sliceLen) len = sliceLen;
    if (len <= 0) {
        if (tid == 0) candCnt[row * SLICES + slice] = 0u;
        return;
    }
    const float t = temps[row];
    const float* lg = logits + (size_t)row * (size_t)V;

    for (int i = tid; i < NBL; i += 256) h[i] = 0u;
    if (tid == 0) { s_base = 0; sh_lb = 0; }
    __syncthreads();

    // pass 1: histogram + local max (float4; len % 4 == 0 guaranteed by launcher)
    uint32_t um = 0u;
    const float4* p4 = (const float4*)(lg + base);
    const int n4 = len >> 2;
    for (int i = tid; i < n4; i += 256) {
        float4 v = p4[i];
        uint32_t u0 = f2u(v.x / t), u1 = f2u(v.y / t);
        uint32_t u2 = f2u(v.z / t), u3 = f2u(v.w / t);
        atomicAdd(&h[u0 >> LBSH], 1u); atomicAdd(&h[u1 >> LBSH], 1u);
        atomicAdd(&h[u2 >> LBSH], 1u); atomicAdd(&h[u3 >> LBSH], 1u);
        uint32_t m01 = u0 > u1 ? u0 : u1, m23 = u2 > u3 ? u2 : u3;
        uint32_t m = m01 > m23 ? m01 : m23;
        if (m > um) um = m;
    }
#pragma unroll
    for (int o = 32; o > 0; o >>= 1) { uint32_t x = __shfl_xor(um, o); if (x > um) um = x; }
    if (lane == 0) rmx[wv] = um;
    __syncthreads();
    if (tid == 0) {
        uint32_t m = rmx[0];
        for (int w = 1; w < 4; w++) if (rmx[w] > m) m = rmx[w];
        rmx[0] = m;
    }
    __syncthreads();
    const int hib = (int)(rmx[0] >> LBSH);

    // wave0: descending descent for the bin of the CLOC-th largest
    if (tid < 64) {
        uint32_t S = 0;
        for (int r0 = hib; r0 >= 0; r0 -= 64) {
            int b = r0 - lane;
            uint32_t w = (b >= 0) ? h[b] : 0u;
            uint32_t incl = wave_incl_u(w);
            uint32_t Sb = S + incl - w;
            bool cross = (Sb < CLOC) && (Sb + w >= CLOC);
            unsigned long long m = __ballot(cross);
            if (m) {
                int l = (int)__ffsll(m) - 1;
                if (lane == l) sh_lb = b;
                break;
            }
            S += __shfl(incl, 63);
        }
    }
    __syncthreads();
    const uint32_t lb = (uint32_t)sh_lb << LBSH;

    // pass 2: collect all u >= lb in deterministic index order (L2-hot re-read)
    uint32_t* cu = cand_u + ((size_t)row * SLICES + slice) * SUBCAP;
    int* cix = cand_ix + ((size_t)row * SLICES + slice) * SUBCAP;
    for (int c0 = 0; c0 < len; c0 += 1024) {
        const int i0 = c0 + tid * 4;
        bool k0 = false, k1b = false, k2b = false, k3b = false;
        uint32_t u0 = 0, u1 = 0, u2 = 0, u3 = 0;
        if (i0 < len) {  // len % 4 == 0 -> all 4 valid
            float4 v = *(const float4*)(lg + base + i0);
            u0 = f2u(v.x / t); u1 = f2u(v.y / t);
            u2 = f2u(v.z / t); u3 = f2u(v.w / t);
            k0 = (u0 >= lb); k1b = (u1 >= lb); k2b = (u2 >= lb); k3b = (u3 >= lb);
        }
        int cnt = (int)k0 + (int)k1b + (int)k2b + (int)k3b;
        int inc = cnt;
#pragma unroll
        for (int o = 1; o < 64; o <<= 1) {
            int x = __shfl_up(inc, (unsigned)o);
            if (lane >= o) inc += x;
        }
        if (lane == 63) wsum[wv] = inc;
        __syncthreads();
        int woff = 0;
        for (int w = 0; w < wv; w++) woff += wsum[w];
        const int tot = wsum[0] + wsum[1] + wsum[2] + wsum[3];
        int p = s_base + woff + inc - cnt;
        if (k0)  { if (p < SUBCAP) { cu[p] = u0; cix[p] = base + i0;     } p++; }
        if (k1b) { if (p < SUBCAP) { cu[p] = u1; cix[p] = base + i0 + 1; } p++; }
        if (k2b) { if (p < SUBCAP) { cu[p] = u2; cix[p] = base + i0 + 2; } p++; }
        if (k3b) { if (p < SUBCAP) { cu[p] = u3; cix[p] = base + i0 + 3; } p++; }
        __syncthreads();
        if (tid == 0) s_base += tot;
        __syncthreads();
    }
    if (tid == 0) {
        int c = s_base; if (c > SUBCAP) c = SUBCAP;
        candCnt[row * SLICES + slice] = (uint32_t)c;
    }
}

// ---------------- K4': per-row finalize over <=12288 candidates ----------------

static __device__ __forceinline__ unsigned long long shflxor_u64(unsigned long long v, int o) {
    uint32_t lo = (uint32_t)v, hi = (uint32_t)(v >> 32);
    lo = __shfl_xor(lo, o); hi = __shfl_xor(hi, o);
    return ((unsigned long long)hi << 32) | (unsigned long long)lo;
}
// 512-thread block sum (8 waves)
static __device__ float k4_blk_sum(float v, float* rbuf) {
#pragma unroll
    for (int o = 32; o > 0; o >>= 1) v += __shfl_xor(v, o);
    const int wv = threadIdx.x >> 6;
    if ((threadIdx.x & 63) == 0) rbuf[wv] = v;
    __syncthreads();
    float r = (threadIdx.x < 8) ? rbuf[threadIdx.x] : 0.f;
    if (threadIdx.x < 64) {
#pragma unroll
        for (int o = 4; o > 0; o >>= 1) r += __shfl_xor(r, o);
        if (threadIdx.x == 0) rbuf[0] = r;
    }
    __syncthreads();
    r = rbuf[0];
    __syncthreads();
    return r;
}
static __device__ unsigned long long k4_blk_max_u64(unsigned long long v, unsigned long long* rbuf) {
#pragma unroll
    for (int o = 32; o > 0; o >>= 1) { unsigned long long t = shflxor_u64(v, o); if (t > v) v = t; }
    const int wv = threadIdx.x >> 6;
    if ((threadIdx.x & 63) == 0) rbuf[wv] = v;
    __syncthreads();
    unsigned long long r = (threadIdx.x < 8) ? rbuf[threadIdx.x] : 0ull;
    if (threadIdx.x < 64) {
#pragma unroll
        for (int o = 4; o > 0; o >>= 1) { unsigned long long t2 = shflxor_u64(r, o); if (t2 > r) r = t2; }
        if (threadIdx.x == 0) rbuf[0] = r;
    }
    __syncthreads();
    r = rbuf[0];
    __syncthreads();
    return r;
}

__global__ __launch_bounds__(512, 1) void k4_final(
    const int* __restrict__ topks, const float* __restrict__ topps,
    const float* __restrict__ minps, const float* __restrict__ noise,
    const uint32_t* __restrict__ candCnt, const uint32_t* __restrict__ cand_u,
    const int* __restrict__ cand_ix, int* __restrict__ out, int V)
{
    const int row = blockIdx.x, tid = threadIdx.x;
    __shared__ uint32_t s_u[CAPT];
    __shared__ int s_ix[CAPT];
    __shared__ uint32_t h[256];        // aliased as float* for weighted levels
    __shared__ int s_off[SLICES + 1];
    __shared__ float rbuf[8];
    __shared__ unsigned long long rbufu[8];
    __shared__ int sh_bin; __shared__ uint32_t sh_above; __shared__ float sh_S;

    if (tid == 0) {
        int a = 0;
        for (int s = 0; s < SLICES; s++) {
            s_off[s] = a;
            int c = (int)candCnt[row * SLICES + s];
            if (c > SUBCAP) c = SUBCAP;
            a += c;
        }
        s_off[SLICES] = a;
    }
    __syncthreads();
    const int n = s_off[SLICES];
    for (int s = 0; s < SLICES; s++) {
        const int o0 = s_off[s], c = s_off[s + 1] - o0;
        const size_t gb = ((size_t)row * SLICES + s) * SUBCAP;
        for (int j = tid; j < c; j += 512) {
            s_u[o0 + j] = cand_u[gb + j];
            s_ix[o0 + j] = cand_ix[gb + j];
        }
    }
    __syncthreads();

    // row max (max element is always a candidate)
    uint32_t um = 0u;
    for (int i = tid; i < n; i += 512) { uint32_t u = s_u[i]; if (u > um) um = u; }
    const uint32_t umax = (uint32_t)k4_blk_max_u64((unsigned long long)um, rbufu);

    int k = topks[row]; if (k < 1) k = 1; if (k > V) k = V;

    // ---- exact top-k threshold: 4-level radix descent on counts ----
    uint32_t prefix = 0u, tk = (uint32_t)k;
#pragma unroll
    for (int l = 0; l < 4; l++) {
        const int sh = 24 - 8 * l;
        if (tid < 256) h[tid] = 0u;
        __syncthreads();
        for (int i = tid; i < n; i += 512) {
            uint32_t u = s_u[i];
            if (l == 0 || (u >> (sh + 8)) == prefix) atomicAdd(&h[(u >> sh) & 255u], 1u);
        }
        __syncthreads();
        wave_desc_count(h, 255, 0, tk, &sh_bin, &sh_above);
        __syncthreads();
        int b = sh_bin; if (b < 0) b = 0;
        uint32_t ab = sh_above;
        prefix = (prefix << 8) | (uint32_t)b;
        tk = (tk > ab) ? (tk - ab) : 1u;
        __syncthreads();
    }
    const uint32_t uk = prefix;

    // ---- W over kept ----
    float wl = 0.f;
    for (int i = tid; i < n; i += 512) { uint32_t u = s_u[i]; if (u >= uk) wl += expf(u2f(u)); }
    const float W = k4_blk_sum(wl, rbuf);
    const float pW = topps[row] * W;
    const float maxw = expf(u2f(umax));

    // ---- top-p boundary (mask kept u <= up); Z2 from descent suffix ----
    uint32_t up = 0u; float Z2 = W;
    if (pW <= 0.f) {
        up = umax - 1u; Z2 = maxw;
    } else {
        float* fh = (float*)h;
        uint32_t pfx = 0u; float Sbase = 0.f; bool done = false;
        for (int l = 0; l < 4 && !done; l++) {
            const int sh = 24 - 8 * l;
            if (tid < 256) fh[tid] = 0.f;
            __syncthreads();
            for (int i = tid; i < n; i += 512) {
                uint32_t u = s_u[i];
                if (u >= uk && (l == 0 || (u >> (sh + 8)) == pfx))
                    atomicAdd(&fh[(u >> sh) & 255u], expf(u2f(u)));
            }
            __syncthreads();
            if (l < 3) wave_desc_wcross(fh, 255, 0, Sbase, pW, &sh_bin, &sh_S);
            else       wave_desc_wvalue(fh, 255, 0, Sbase, pW, &sh_bin, &sh_S);
            __syncthreads();
            const int b = sh_bin; const float Snew = sh_S;
            if (b < 0) {
                if (l == 0) { up = 0u; Z2 = W; }
                else {
                    uint32_t basev = pfx << (sh + 8);
                    up = basev ? basev - 1u : 0u;
                    Z2 = Snew;
                }
                done = true;
            } else {
                pfx = (pfx << 8) | (uint32_t)b;
                Sbase = Snew;
                if (l == 3) { up = pfx; Z2 = Snew; }
            }
            __syncthreads();
        }
        if (up >= umax) { up = umax - 1u; Z2 = maxw; }
    }

    // ---- min-p threshold ----
    const float mp = minps[row];
    const bool use_mp = (mp > 0.f);
    const float A = use_mp ? (maxw / Z2) * mp : 0.f;

    // ---- Z3 over finally-kept ----
    float z3l = 0.f;
    for (int i = tid; i < n; i += 512) {
        uint32_t u = s_u[i];
        if (u >= uk && u > up) {
            float w = expf(u2f(u));
            if (!(use_mp && (w / Z2) < A)) z3l += w;
        }
    }
    const float Z3 = k4_blk_sum(z3l, rbuf);

    // ---- argmax of (w/Z3)/max(noise,1e-10); smallest index on ties ----
    unsigned long long best = 0ull;
    for (int i = tid; i < n; i += 512) {
        uint32_t u = s_u[i];
        if (u >= uk && u > up) {
            float w = expf(u2f(u));
            if (!(use_mp && (w / Z2) < A)) {
                int idx = s_ix[i];
                float nz = fmaxf(noise[(size_t)row * (size_t)V + idx], 1e-10f);
                float sc = (w / Z3) / nz;
                unsigned long long pk = ((unsigned long long)__float_as_uint(sc) << 32)
                                      | (unsigned long long)(~(uint32_t)idx);
                if (pk > best) best = pk;
            }
        }
    }
    best = k4_blk_max_u64(best, rbufu);
    if (tid == 0) out[row] = (int)(~(uint32_t)(best & 0xffffffffull));
}

// ---------------- fallback: monolithic single-kernel path (ws too small / odd V) ----------------

#define FNT 1024
#define FNB1 16384
#define FL1SH 18
#define FCAP 8192

static __device__ float fblk_max_f(float v, float* buf) {
    int tid = threadIdx.x;
    buf[tid] = v; __syncthreads();
    for (int o = FNT / 2; o > 0; o >>= 1) {
        if (tid < o) buf[tid] = fmaxf(buf[tid], buf[tid + o]);
        __syncthreads();
    }
    float r = buf[0]; __syncthreads();
    return r;
}
static __device__ float fblk_sum_f(float v, float* buf) {
    int tid = threadIdx.x;
    buf[tid] = v; __syncthreads();
    for (int o = FNT / 2; o > 0; o >>= 1) {
        if (tid < o) buf[tid] += buf[tid + o];
        __syncthreads();
    }
    float r = buf[0]; __syncthreads();
    return r;
}

__global__ __launch_bounds__(FNT, 1) void sampler_fallback_kernel(
    const float* __restrict__ logits, const float* __restrict__ temps,
    const int* __restrict__ topks, const float* __restrict__ topps,
    const float* __restrict__ minps, const float* __restrict__ noise,
    int* __restrict__ out, int V)
{
    __shared__ uint32_t s_hist[FNB1];
    __shared__ uint32_t s_cand[FCAP];
    __shared__ float    s_red[FNT];
    __shared__ uint32_t s_h2[512];
    __shared__ int      sh_bin;
    __shared__ uint32_t sh_above;
    __shared__ int      sh_nc;
    __shared__ int      sh_binw;
    __shared__ float    sh_S;

    const int row = blockIdx.x;
    const int tid = threadIdx.x;
    const int lane = tid & 63;
    const float t  = temps[row];
    const float pp = topps[row];
    const float mp = minps[row];
    int k = topks[row];
    if (k < 1) k = 1;
    if (k > V) k = V;
    const float* lg = logits + (size_t)row * (size_t)V;
    const float* nz = noise  + (size_t)row * (size_t)V;

    for (int i = tid; i < FNB1; i += FNT) s_hist[i] = 0u;
    __syncthreads();

    float lmax = -INFINITY;
    for (int i = tid; i < V; i += FNT) {
        float x = lg[i] / t;
        lmax = fmaxf(lmax, x);
        atomicAdd(&s_hist[f2u(x) >> FL1SH], 1u);
    }
    const float M = fblk_max_f(lmax, s_red);
    const uint32_t umax = f2u(M);
    const int bmax = (int)(umax >> FL1SH);

    if (tid == 0) sh_bin = -1;
    __syncthreads();
    wave_desc_count(s_hist, bmax, 0, (uint32_t)k, &sh_bin, &sh_above);
    __syncthreads();
    const int b1 = sh_bin;
    const uint32_t cntHi = sh_above;

    float* wh = reinterpret_cast<float*>(s_hist);
    for (int i = tid; i < FNB1; i += FNT) wh[i] = 0.f;
    if (tid == 0) sh_nc = 0;
    __syncthreads();
    for (int i = tid; i < V; i += FNT) {
        float x = lg[i] / t;
        uint32_t u = f2u(x);
        atomicAdd(&wh[u >> FL1SH], expf(x - M));
        bool want = ((int)(u >> FL1SH) == b1);
        unsigned long long mb = __ballot(want);
        if (want) {
            int leader = (int)__ffsll(mb) - 1;
            int off = (int)__popcll(mb & ((1ull << lane) - 1ull));
            int base = 0;
            if (lane == leader) base = atomicAdd(&sh_nc, (int)__popcll(mb));
            base = __shfl(base, leader);
            int p = base + off;
            if (p < FCAP) s_cand[p] = u;
        }
    }
    __syncthreads();
    int nc = sh_nc; if (nc > FCAP) nc = FCAP;
    const uint32_t kk2 = (uint32_t)k - cntHi;

    for (int i = tid; i < 512; i += FNT) s_h2[i] = 0u;
    __syncthreads();
    for (int i = tid; i < nc; i += FNT) atomicAdd(&s_h2[(s_cand[i] >> 9) & 511u], 1u);
    __syncthreads();
    if (tid == 0) sh_bin = -1;
    __syncthreads();
    wave_desc_count(s_h2, 511, 0, kk2, &sh_bin, &sh_above);
    __syncthreads();
    const int c2 = sh_bin;
    const uint32_t kk3 = kk2 - sh_above;

    for (int i = tid; i < 512; i += FNT) s_h2[i] = 0u;
    __syncthreads();
    for (int i = tid; i < nc; i += FNT) {
        uint32_t u = s_cand[i];
        if ((int)((u >> 9) & 511u) == c2) atomicAdd(&s_h2[u & 511u], 1u);
    }
    __syncthreads();
    if (tid == 0) sh_bin = -1;
    __syncthreads();
    wave_desc_count(s_h2, 511, 0, kk3, &sh_bin, &sh_above);
    __syncthreads();
    const uint32_t uk = ((uint32_t)b1 << FL1SH) | ((uint32_t)c2 << 9) | (uint32_t)sh_bin;

    float wl = 0.f;
    for (int i = tid; i < nc; i += FNT) {
        uint32_t u = s_cand[i];
        if (u >= uk) wl += expf(u2f(u) - M);
    }
    const float Wb1 = fblk_sum_f(wl, s_red);
    if (tid == 0) wh[b1] = Wb1;
    __syncthreads();
    float sl = 0.f;
    for (int i = tid; i < FNB1; i += FNT)
        if (i >= b1 && i <= bmax) sl += wh[i];
    const float W = fblk_sum_f(sl, s_red);
    const float pW = pp * W;

    uint32_t up = 0u;
    float Z2 = W;
    if (pW <= 0.f) {
        up = umax - 1u;
        Z2 = 1.0f;
    } else {
        if (tid == 0) sh_binw = -1;
        __syncthreads();
        wave_desc_wcross(wh, bmax, b1, 0.f, pW, &sh_binw, &sh_S);
        __syncthreads();
        const int cs = sh_binw;
        if (cs >= 0) {
            const float S1 = sh_S;
            if (cs != b1) {
                if (tid == 0) sh_nc = 0;
                __syncthreads();
                for (int i = tid; i < V; i += FNT) {
                    float x = lg[i] / t;
                    uint32_t u = f2u(x);
                    bool want = (u >= uk) && ((int)(u >> FL1SH) == cs);
                    unsigned long long mb = __ballot(want);
                    if (want) {
                        int leader = (int)__ffsll(mb) - 1;
                        int off = (int)__popcll(mb & ((1ull << lane) - 1ull));
                        int base = 0;
                        if (lane == leader) base = atomicAdd(&sh_nc, (int)__popcll(mb));
                        base = __shfl(base, leader);
                        int p = base + off;
                        if (p < FCAP) s_cand[p] = u;
                    }
                }
                __syncthreads();
                nc = sh_nc; if (nc > FCAP) nc = FCAP;
            }
            float* wh2 = reinterpret_cast<float*>(s_h2);
            for (int i = tid; i < 512; i += FNT) wh2[i] = 0.f;
            __syncthreads();
            for (int i = tid; i < nc; i += FNT) {
                uint32_t u = s_cand[i];
                if (u >= uk) atomicAdd(&wh2[(u >> 9) & 511u], expf(u2f(u) - M));
            }
            __syncthreads();
            if (tid == 0) sh_binw = -1;
            __syncthreads();
            wave_desc_wcross(wh2, 511, 0, S1, pW, &sh_binw, &sh_S);
            __syncthreads();
            const int c2p = sh_binw;
            if (c2p < 0) {
                uint32_t basev = (uint32_t)cs << FL1SH;
                up = basev ? basev - 1u : 0u;
                Z2 = sh_S;
            } else {
                const float S2 = sh_S;
                for (int i = tid; i < 512; i += FNT) wh2[i] = 0.f;
                __syncthreads();
                for (int i = tid; i < nc; i += FNT) {
                    uint32_t u = s_cand[i];
                    if (u >= uk && (int)((u >> 9) & 511u) == c2p)
                        atomicAdd(&wh2[u & 511u], expf(u2f(u) - M));
                }
                __syncthreads();
                if (tid == 0) sh_binw = -1;
                __syncthreads();
                wave_desc_wvalue(wh2, 511, 0, S2, pW, &sh_binw, &sh_S);
                __syncthreads();
                if (sh_binw < 0) {
                    uint32_t basev = ((uint32_t)cs << FL1SH) | ((uint32_t)c2p << 9);
                    up = basev ? basev - 1u : 0u;
                    Z2 = sh_S;
                } else {
                    up = ((uint32_t)cs << FL1SH) | ((uint32_t)c2p << 9) | (uint32_t)sh_binw;
                    Z2 = sh_S;
                }
            }
        }
        if (up >= umax) { up = umax - 1u; Z2 = 1.0f; }
    }
    __syncthreads();

    const bool use_mp = (mp > 0.f);
    const float thr = mp * (1.0f / Z2);

    float zl = 0.f;
    for (int i = tid; i < V; i += FNT) {
        float x = lg[i] / t;
        uint32_t u = f2u(x);
        if (u >= uk && u > up) {
            float w = expf(x - M);
            if (use_mp && (w / Z2) < thr) continue;
            zl += w;
        }
    }
    const float Z3 = fblk_sum_f(zl, s_red);

    float bs = -1.f; int bi = 0x7fffffff;
    for (int i = tid; i < V; i += FNT) {
        float x = lg[i] / t;
        uint32_t u = f2u(x);
        if (u >= uk && u > up) {
            float w = expf(x - M);
            if (use_mp && (w / Z2) < thr) continue;
            float sc = (w / Z3) / fmaxf(nz[i], 1e-10f);
            if (sc > bs) { bs = sc; bi = i; }
        }
    }
    s_red[tid] = bs;
    int* ibuf = reinterpret_cast<int*>(s_cand);
    ibuf[tid] = bi;
    __syncthreads();
    for (int o = FNT / 2; o > 0; o >>= 1) {
        if (tid < o) {
            float v2 = s_red[tid + o]; int i2 = ibuf[tid + o];
            if (v2 > s_red[tid] || (v2 == s_red[tid] && i2 < ibuf[tid])) {
                s_red[tid] = v2; ibuf[tid] = i2;
            }
        }
        __syncthreads();
    }
    if (tid == 0) out[row] = ibuf[0];
}

// ---------------- launch ----------------

extern "C" void kernel_launch(void* const* d_in, const int* in_sizes, int n_in,
                              void* d_out, int out_size, void* d_ws, size_t ws_size,
                              hipStream_t stream) {
    const float* logits = (const float*)d_in[0];
    const float* temps  = (const float*)d_in[1];
    const int*   topks  = (const int*)d_in[2];
    const float* topps  = (const float*)d_in[3];
    const float* minps  = (const float*)d_in[4];
    const float* noise  = (const float*)d_in[5];
    const int B = in_sizes[1];
    const int V = in_sizes[0] / B;
    int* out = (int*)d_out;

    const int sliceLen = (((V + SLICES - 1) / SLICES) + 1023) & ~1023;

    const size_t offCU  = 0;
    const size_t offCI  = offCU + (size_t)B * SLICES * SUBCAP * 4;
    const size_t offCnt = offCI + (size_t)B * SLICES * SUBCAP * 4;
    const size_t need   = offCnt + (size_t)B * SLICES * 4;

    if (ws_size >= need && (V & 3) == 0 && (size_t)SLICES * (size_t)sliceLen >= (size_t)V) {
        char* ws = (char*)d_ws;
        uint32_t* cand_u  = (uint32_t*)(ws + offCU);
        int*      cand_ix = (int*)(ws + offCI);
        uint32_t* candCnt = (uint32_t*)(ws + offCnt);

        dim3 gslice(SLICES, B);
        k1_collect<<<gslice, 256, 0, stream>>>(logits, temps, cand_u, cand_ix, candCnt, V, sliceLen);
        k4_final<<<B, 512, 0, stream>>>(topks, topps, minps, noise, candCnt, cand_u, cand_ix, out, V);
    } else {
        sampler_fallback_kernel<<<B, FNT, 0, stream>>>(logits, temps, topks, topps, minps, noise, out, V);
    }
}